// Round 11
// baseline (81.972 us; speedup 1.0000x reference)
//
#include <hip/hip_runtime.h>
#include <hip/hip_bf16.h>
#include <math.h>

#define NSLICE 2048
#define NH 133     // output spatial size (int(128*1+4)+1)
#define NP 144     // padded to 9 tiles of 16
#define NT 576     // 9 waves per block

// LDS map (78,848 B; x2 = 157,696 <= 160 KiB -> 2 blocks/CU):
//   [0, 32768)       X_fm   : 32 frags (pt*4+kk) x 1024 B, bf16 fragment-major
//   [32768, 69632)   M1_fm  : 36 frags (it*4+kk) x 1024 B, bf16 fragment-major
//   [69632, 78848)   scratch: 9 waves x 1024 B (per-wave repack, reused per kk)
#define M1B  32768
#define SCR  69632
#define LDSB 78848

typedef __attribute__((ext_vector_type(8))) short bf16x8;   // 8 bf16 = 4 VGPRs
typedef __attribute__((ext_vector_type(4))) float f32x4;

typedef __attribute__((address_space(3))) unsigned int  lds_u32;
typedef const __attribute__((address_space(1))) unsigned int glb_u32;

#define GLOAD_LDS16(gsrc, ldst) \
    __builtin_amdgcn_global_load_lds((glb_u32*)(gsrc), (lds_u32*)(ldst), 16, 0, 0)

__device__ __forceinline__ unsigned f2bf(float f) {
    __hip_bfloat16 h = __float2bfloat16(f);   // round-to-nearest-even
    union { __hip_bfloat16 b; unsigned short u; } c; c.b = h; return (unsigned)c.u;
}

// ---------------------------------------------------------------------------
// prep_M: combined (IDCT * mask * DCT) matrices, bf16, in workspace.
//   M[row, p] = sum_{u=0}^{127} D2[u,row] * mask[u] * D1[u,p]
// M1 emitted FRAGMENT-MAJOR (ready for direct LDS copy); M2 row-major.
// ---------------------------------------------------------------------------
__global__ void prep_M(const float* __restrict__ rw,
                       unsigned short* __restrict__ M1,
                       unsigned short* __restrict__ M2) {
    __shared__ float t1[512];
    __shared__ float t2[532];
    const int b   = blockIdx.x;        // 0..287
    const int m   = b / NP;            // 0 -> M1, 1 -> M2
    const int row = b - m * NP;        // 0..143
    const int p   = threadIdx.x;       // 0..127

    const float c1  = (float)(M_PI / 256.0);
    const float c2  = (float)(M_PI / 266.0);
    const float s1n = 0.125f;                  // sqrt(2/128)
    const float s10 = 0.08838834764831844f;    // s1n/sqrt(2)
    const float s2n = 0.12262786485246718f;    // sqrt(2/133)
    const float s20 = 0.08671099951921386f;    // s2n/sqrt(2)

    for (int k = p; k < 512; k += 128) t1[k] = cosf((float)k * c1) * s1n;
    for (int k = p; k < 532; k += 128) t2[k] = cosf((float)k * c2) * s2n;
    __syncthreads();

    float val = 0.0f;
    if (row < NH) {
        float r = rw[m];
        float minr = fmaxf((1.0f - 4.0f) / 128.0f, 0.0f);
        r = fminf(fmaxf(r, minr), 2.0f);
        const float crop = 128.0f * r;

        const int tp = 2 * p + 1;
        const int ti = 2 * row + 1;
        float acc = s10 * s20;        // u = 0 term (mask(0) == 1 since crop >= 0)
        int a1 = 0, a2 = 0;
        for (int u = 1; u < 128; ++u) {
            a1 = (a1 + tp) & 511;
            a2 += ti; if (a2 >= 532) a2 -= 532;
            float mask = fminf(fmaxf((4.0f + crop - (float)u) * 0.25f, 0.0f), 1.0f);
            acc = fmaf(t1[a1] * mask, t2[a2], acc);
        }
        val = acc;
    }
    const unsigned short v16 = (unsigned short)f2bf(val);
    if (m == 0) {
        const int it = row >> 4, rr = row & 15;
        const int k2 = p >> 5, gg = (p >> 3) & 3, e = p & 7;
        M1[(size_t)((it * 4 + k2) * 512 + (gg * 16 + rr) * 8 + e)] = v16;
    } else {
        M2[(size_t)row * 128 + p] = v16;
    }
}

// ---------------------------------------------------------------------------
// dct_resize: one 576-thread block (9 waves) per (b,c) slice, ONE barrier.
//   staging (pre-barrier):
//     - X: waves 0-7, 8 global_load_dwordx4 per lane issued via INLINE ASM
//       (back-to-back, compiler cannot serialize them) -> one HBM round trip;
//       M1_fm -> LDS async global_load_lds concurrently; single vmcnt(0)
//       drain + sched_barrier (rule-18 fence) before the cvt+write pass.
//     - cvt fp32->bf16, write X_fm fragment-major (lane*16, conflict-clean)
//   post-barrier (waves fully independent, no more syncs):
//     Stage A: wave w owns j-tile w: T[j0+r][p] via 32 MFMA (X_fm reads)
//     repack : per-wave 1KB scratch (in-wave DS ordering, barrier-free)
//     Stage B: out[:, j0+r] via 36 MFMA (M1_fm lane*16 reads); guarded stores
// ---------------------------------------------------------------------------
__global__ __launch_bounds__(NT, 5) void dct_resize(
        const float* __restrict__ x,
        const unsigned short* __restrict__ M1f,
        const unsigned short* __restrict__ M2,
        float* __restrict__ out) {
    __shared__ __align__(16) unsigned char lds[LDSB];

    const int tid  = threadIdx.x;
    const int w    = tid >> 6;      // wave 0..8
    const int lane = tid & 63;
    const int r    = lane & 15;     // fragment row/col index
    const int g    = lane >> 4;     // k-group 0..3

    const float* xs = x + (size_t)blockIdx.x * (128 * 128);
    float*       os = out + (size_t)blockIdx.x * (NH * NH);

    const int j0 = w * 16;          // this wave's output-column tile

    // ---- X loads: 8 dwordx4 per lane, batch-issued via inline asm ----
    f32x4 xlo[4], xhi[4];
    if (w < 8) {
        #pragma unroll
        for (int v = 0; v < 4; ++v) {
            const int f  = v * 8 + w;        // fragment id 0..31
            const int pt = f >> 2, k2 = f & 3;
            const float* src = xs + (size_t)(pt * 16 + r) * 128 + k2 * 32 + g * 8;
            asm volatile("global_load_dwordx4 %0, %1, off"
                         : "=v"(xlo[v]) : "v"(src) : "memory");
            asm volatile("global_load_dwordx4 %0, %1, off offset:16"
                         : "=v"(xhi[v]) : "v"(src) : "memory");
        }
    }

    // ---- M1_fm -> LDS async (in flight alongside the X loads) ----
    #pragma unroll
    for (int v = 0; v < 4; ++v)
        GLOAD_LDS16(M1f + (size_t)(v * NT + tid) * 8,
                    lds + M1B + (v * NT + tid) * 16);

    // ---- per-wave M2 register fragments (L2-hot) ----
    bf16x8 bm2[4];
    #pragma unroll
    for (int kk = 0; kk < 4; ++kk)
        bm2[kk] = *(const bf16x8*)(M2 + (size_t)(j0 + r) * 128 + kk * 32 + g * 8);

    // ---- single drain for all staging loads; fence VALU motion (rule 18) ----
    asm volatile("s_waitcnt vmcnt(0)" ::: "memory");
    __builtin_amdgcn_sched_barrier(0);

    // ---- cvt + write X_fm fragment-major ----
    if (w < 8) {
        #pragma unroll
        for (int v = 0; v < 4; ++v) {
            const int f = v * 8 + w;
            uint4 pkt;
            pkt.x = f2bf(xlo[v].x) | (f2bf(xlo[v].y) << 16);
            pkt.y = f2bf(xlo[v].z) | (f2bf(xlo[v].w) << 16);
            pkt.z = f2bf(xhi[v].x) | (f2bf(xhi[v].y) << 16);
            pkt.w = f2bf(xhi[v].z) | (f2bf(xhi[v].w) << 16);
            *(uint4*)(lds + f * 1024 + lane * 16) = pkt;
        }
    }
    __syncthreads();   // the ONLY barrier

    // ---- Stage A: T[j0+r][p] = sum_q X[p][q] * M2[j0+r][q] ----
    uint2 u2[8];
    #pragma unroll
    for (int pt = 0; pt < 8; ++pt) {
        f32x4 acc = {0.f, 0.f, 0.f, 0.f};
        #pragma unroll
        for (int kk = 0; kk < 4; ++kk) {
            bf16x8 a = *(const bf16x8*)(lds + (pt * 4 + kk) * 1024 + lane * 16);
            acc = __builtin_amdgcn_mfma_f32_16x16x32_bf16(a, bm2[kk], acc, 0, 0, 0);
        }
        // lane holds T[j0+r][pt*16 + g*4 + q], q = 0..3 (D layout)
        u2[pt].x = f2bf(acc[0]) | (f2bf(acc[1]) << 16);
        u2[pt].y = f2bf(acc[2]) | (f2bf(acc[3]) << 16);
    }

    // ---- per-wave repack: D layout (4-consec p) -> B-fragment (8-consec p)
    // In-wave DS ops processed in order -> no barrier needed (R4/R10-proven).
    unsigned char* scr = lds + SCR + w * 1024;
    bf16x8 bfrag[4];
    #pragma unroll
    for (int kk = 0; kk < 4; ++kk) {
        *(uint2*)(scr + (g)     * 128 + r * 8) = u2[2 * kk];
        *(uint2*)(scr + (4 + g) * 128 + r * 8) = u2[2 * kk + 1];
        const uint2 lo2 = *(const uint2*)(scr + (2 * g)     * 128 + r * 8);
        const uint2 hi2 = *(const uint2*)(scr + (2 * g + 1) * 128 + r * 8);
        union { uint4 u; bf16x8 b; } cv;
        cv.u = make_uint4(lo2.x, lo2.y, hi2.x, hi2.y);
        bfrag[kk] = cv.b;
    }

    // ---- Stage B: out[i][j0+r] = sum_p M1[i][p] * T[j0+r][p] ----
    const int jc = j0 + r;
    #pragma unroll
    for (int it = 0; it < 9; ++it) {
        f32x4 acc = {0.f, 0.f, 0.f, 0.f};
        #pragma unroll
        for (int kk = 0; kk < 4; ++kk) {
            bf16x8 a = *(const bf16x8*)(lds + M1B + (it * 4 + kk) * 1024 + lane * 16);
            acc = __builtin_amdgcn_mfma_f32_16x16x32_bf16(a, bfrag[kk], acc, 0, 0, 0);
        }
        if (jc < NH) {
            #pragma unroll
            for (int q = 0; q < 4; ++q) {
                const int i = it * 16 + g * 4 + q;
                if (i < NH) os[(size_t)i * NH + jc] = acc[q];
            }
        }
    }
}

extern "C" void kernel_launch(void* const* d_in, const int* in_sizes, int n_in,
                              void* d_out, int out_size, void* d_ws, size_t ws_size,
                              hipStream_t stream) {
    const float* x  = (const float*)d_in[0];
    const float* rw = (const float*)d_in[1];
    float* outp = (float*)d_out;
    unsigned short* M1 = (unsigned short*)d_ws;     // 18432 ushorts, fragment-major
    unsigned short* M2 = M1 + 18432;                // 18432 ushorts, row-major

    prep_M<<<dim3(2 * NP), dim3(128), 0, stream>>>(rw, M1, M2);
    dct_resize<<<dim3(NSLICE), dim3(NT), 0, stream>>>(x, M1, M2, outp);
}